// Round 2
// baseline (10873.042 us; speedup 1.0000x reference)
//
#include <hip/hip_runtime.h>
#include <hip/hip_bf16.h>

#define S_LEN 512
#define BATCH 64
#define H_DIM 1024
#define NLAYER 2
#define G3 3072           // 3*H
#define CS 128            // timestep chunk for gi buffer
#define CROWS (CS*BATCH)  // 8192 rows per proj chunk

typedef __bf16 bf16_t;
typedef __bf16 bf16x8_t __attribute__((ext_vector_type(8)));
typedef __bf16 bf16x4_t __attribute__((ext_vector_type(4)));
typedef float f32x4 __attribute__((ext_vector_type(4)));

__device__ __forceinline__ float sigmoidf_(float x) { return 1.0f / (1.0f + __expf(-x)); }

__device__ __forceinline__ void split2(float f, bf16_t& hi, bf16_t& lo) {
    hi = (bf16_t)f;
    lo = (bf16_t)(f - (float)hi);
}

// ---------------- split f32 -> (bf16 hi, bf16 lo) ----------------
__global__ void split_kernel(const float* __restrict__ in, bf16_t* __restrict__ hi,
                             bf16_t* __restrict__ lo, int n4) {
    int i = blockIdx.x * blockDim.x + threadIdx.x;
    int stride = gridDim.x * blockDim.x;
    for (; i < n4; i += stride) {
        f32x4 v = *(const f32x4*)(in + 4 * (size_t)i);
        bf16x4_t h, l;
#pragma unroll
        for (int j = 0; j < 4; ++j) { bf16_t a, b; split2(v[j], a, b); h[j] = a; l[j] = b; }
        *(bf16x4_t*)(hi + 4 * (size_t)i) = h;
        *(bf16x4_t*)(lo + 4 * (size_t)i) = l;
    }
}

// ---------------- projection GEMM: C[M,N] = A[M,K] * W[N,K]^T + bias ----------------
// split-bf16: C = Ah*Wh + Ah*Wl + Al*Wh.  M=8192 (chunk), N=3072, K=1024.
// 128x128 tile, BK=64, 4 waves (2x2), each wave 64x64 = 4x4 frags of 16x16x32.
__global__ __launch_bounds__(256) void proj_kernel(
    const bf16_t* __restrict__ Ah, const bf16_t* __restrict__ Al,  // [rows][1024] (chunk-offset)
    const bf16_t* __restrict__ Wh, const bf16_t* __restrict__ Wl,  // [3072][1024] (layer base)
    const float* __restrict__ bias,                                // [3072]
    float* __restrict__ Cout)                                      // [CROWS][3072]
{
    __shared__ bf16_t sA[2][128][72];  // [hi/lo][row][k] (+8 pad: 2-way banks)
    __shared__ bf16_t sW[2][128][72];
    const int tid = threadIdx.x;
    const int lane = tid & 63;
    const int w = tid >> 6;
    const int wm = w >> 1, wn = w & 1;
    const int bn = blockIdx.x, bm = blockIdx.y;
    const int fr = lane & 15;   // frag row (A) / col (W,C)
    const int fq = lane >> 4;   // 0..3

    f32x4 acc[4][4] = {};

    const bf16_t* A0 = Ah + (size_t)bm * 128 * 1024;
    const bf16_t* A1 = Al + (size_t)bm * 128 * 1024;
    const bf16_t* W0 = Wh + (size_t)bn * 128 * 1024;
    const bf16_t* W1 = Wl + (size_t)bn * 128 * 1024;

    for (int kt = 0; kt < 16; ++kt) {
        const int k0 = kt * 64;
        // stage 128x64 of each array: 1024 groups of 8 bf16, 4 per thread per array
#pragma unroll
        for (int it = 0; it < 4; ++it) {
            int g = tid + it * 256;
            int row = g >> 3, c8 = (g & 7) * 8;
            size_t so = (size_t)row * 1024 + k0 + c8;
            *(bf16x8_t*)&sA[0][row][c8] = *(const bf16x8_t*)(A0 + so);
            *(bf16x8_t*)&sA[1][row][c8] = *(const bf16x8_t*)(A1 + so);
            *(bf16x8_t*)&sW[0][row][c8] = *(const bf16x8_t*)(W0 + so);
            *(bf16x8_t*)&sW[1][row][c8] = *(const bf16x8_t*)(W1 + so);
        }
        __syncthreads();
#pragma unroll
        for (int kk = 0; kk < 2; ++kk) {
            const int koff = kk * 32 + fq * 8;
            bf16x8_t ah[4], al[4], wh8[4], wl8[4];
#pragma unroll
            for (int mt = 0; mt < 4; ++mt) {
                ah[mt] = *(const bf16x8_t*)&sA[0][wm * 64 + mt * 16 + fr][koff];
                al[mt] = *(const bf16x8_t*)&sA[1][wm * 64 + mt * 16 + fr][koff];
            }
#pragma unroll
            for (int nt = 0; nt < 4; ++nt) {
                wh8[nt] = *(const bf16x8_t*)&sW[0][wn * 64 + nt * 16 + fr][koff];
                wl8[nt] = *(const bf16x8_t*)&sW[1][wn * 64 + nt * 16 + fr][koff];
            }
#pragma unroll
            for (int mt = 0; mt < 4; ++mt)
#pragma unroll
                for (int nt = 0; nt < 4; ++nt) {
                    acc[mt][nt] = __builtin_amdgcn_mfma_f32_16x16x32_bf16(ah[mt], wh8[nt], acc[mt][nt], 0, 0, 0);
                    acc[mt][nt] = __builtin_amdgcn_mfma_f32_16x16x32_bf16(ah[mt], wl8[nt], acc[mt][nt], 0, 0, 0);
                    acc[mt][nt] = __builtin_amdgcn_mfma_f32_16x16x32_bf16(al[mt], wh8[nt], acc[mt][nt], 0, 0, 0);
                }
        }
        __syncthreads();
    }
    // epilogue: C/D layout col=lane&15, row=(lane>>4)*4+reg
#pragma unroll
    for (int nt = 0; nt < 4; ++nt) {
        int n = bn * 128 + wn * 64 + nt * 16 + fr;
        float bv = bias[n];
#pragma unroll
        for (int mt = 0; mt < 4; ++mt) {
#pragma unroll
            for (int r = 0; r < 4; ++r) {
                int m = bm * 128 + wm * 64 + mt * 16 + fq * 4 + r;
                Cout[(size_t)m * G3 + n] = acc[mt][nt][r] + bv;
            }
        }
    }
}

// ---------------- one GRU recurrence step (per-launch) ----------------
// grid (128,2): blockIdx.x -> j-slice of 8, blockIdx.y -> batch half of 32.
// 4 waves split K (256 each, 4 chunks of 64), wave-private LDS staging (no barriers
// in main loop). Block GEMM: [32 b] x [24 cols: r0..7,z0..7 | n0..7,pad8] x K=1024.
__global__ __launch_bounds__(256) void rec_step_kernel(
    const float* __restrict__ gi_t,  // [64][3072] for this t
    const bf16_t* __restrict__ Whh,  // [3072][1024] layer base
    const bf16_t* __restrict__ Whl,
    const float* __restrict__ bhl,   // [3072]
    const float* __restrict__ h_in,  // [64][1024]
    float* __restrict__ h_out,       // [64][1024]
    float* __restrict__ out_f32,     // layer1: d_out + t*B*H, else null
    bf16_t* __restrict__ out_hi,     // layer0: seq split slice, else null
    bf16_t* __restrict__ out_lo,
    float* __restrict__ hn_out)      // t==S-1: d_out h_n slot, else null
{
    __shared__ bf16_t sH[4][2][32][72];  // [wave][hi/lo][b][k]
    __shared__ bf16_t sW[4][2][32][72];  // [wave][hi/lo][col(24 real)][k]
    __shared__ float sP[4][32][32];      // split-K partials

    const int tid = threadIdx.x;
    const int lane = tid & 63;
    const int w = tid >> 6;
    const int b0 = blockIdx.y * 32;
    const int j0 = blockIdx.x * 8;
    const int fr = lane & 15, fq = lane >> 4;

    f32x4 acc[2][2] = {};

    for (int ck = 0; ck < 4; ++ck) {
        const int k0 = w * 256 + ck * 64;
        // stage h slice [32][64] f32 -> hi/lo : 512 float4, 8 per lane
#pragma unroll
        for (int it = 0; it < 8; ++it) {
            int g = lane + it * 64;
            int row = g >> 4, c4 = (g & 15) * 4;
            f32x4 v = *(const f32x4*)(h_in + (size_t)(b0 + row) * 1024 + k0 + c4);
            bf16x4_t hh, ll;
#pragma unroll
            for (int j = 0; j < 4; ++j) { bf16_t a, b; split2(v[j], a, b); hh[j] = a; ll[j] = b; }
            *(bf16x4_t*)&sH[w][0][row][c4] = hh;
            *(bf16x4_t*)&sH[w][1][row][c4] = ll;
        }
        // stage W: 24 rows x 64 bf16 (hi & lo): 192 groups of 8, 3 per lane
#pragma unroll
        for (int it = 0; it < 3; ++it) {
            int g = lane + it * 64;
            int row = g >> 3, c8 = (g & 7) * 8;
            int gate = row >> 3, jj = row & 7;
            size_t so = (size_t)(gate * 1024 + j0 + jj) * 1024 + k0 + c8;
            *(bf16x8_t*)&sW[w][0][row][c8] = *(const bf16x8_t*)(Whh + so);
            *(bf16x8_t*)&sW[w][1][row][c8] = *(const bf16x8_t*)(Whl + so);
        }
        // wave-local RAW on LDS: compiler inserts lgkmcnt waits
#pragma unroll
        for (int kk = 0; kk < 2; ++kk) {
            const int koff = kk * 32 + fq * 8;
            bf16x8_t ah[2], al[2], wh8[2], wl8[2];
#pragma unroll
            for (int mt = 0; mt < 2; ++mt) {
                ah[mt] = *(const bf16x8_t*)&sH[w][0][mt * 16 + fr][koff];
                al[mt] = *(const bf16x8_t*)&sH[w][1][mt * 16 + fr][koff];
            }
#pragma unroll
            for (int nt = 0; nt < 2; ++nt) {
                wh8[nt] = *(const bf16x8_t*)&sW[w][0][nt * 16 + fr][koff];
                wl8[nt] = *(const bf16x8_t*)&sW[w][1][nt * 16 + fr][koff];
            }
#pragma unroll
            for (int mt = 0; mt < 2; ++mt)
#pragma unroll
                for (int nt = 0; nt < 2; ++nt) {
                    acc[mt][nt] = __builtin_amdgcn_mfma_f32_16x16x32_bf16(ah[mt], wh8[nt], acc[mt][nt], 0, 0, 0);
                    acc[mt][nt] = __builtin_amdgcn_mfma_f32_16x16x32_bf16(ah[mt], wl8[nt], acc[mt][nt], 0, 0, 0);
                    acc[mt][nt] = __builtin_amdgcn_mfma_f32_16x16x32_bf16(al[mt], wh8[nt], acc[mt][nt], 0, 0, 0);
                }
        }
    }
    // write split-K partials
#pragma unroll
    for (int mt = 0; mt < 2; ++mt)
#pragma unroll
        for (int nt = 0; nt < 2; ++nt)
#pragma unroll
            for (int r = 0; r < 4; ++r)
                sP[w][mt * 16 + fq * 4 + r][nt * 16 + fr] = acc[mt][nt][r];
    __syncthreads();

    // pointwise: 256 threads -> (b 0..31, jj 0..7)
    {
        const int b = tid >> 3, jj = tid & 7;
        const int bg = b0 + b, jg = j0 + jj;
        float ghr = sP[0][b][jj] + sP[1][b][jj] + sP[2][b][jj] + sP[3][b][jj];
        float ghz = sP[0][b][8 + jj] + sP[1][b][8 + jj] + sP[2][b][8 + jj] + sP[3][b][8 + jj];
        float ghn = sP[0][b][16 + jj] + sP[1][b][16 + jj] + sP[2][b][16 + jj] + sP[3][b][16 + jj];
        ghr += bhl[jg];
        ghz += bhl[1024 + jg];
        ghn += bhl[2048 + jg];
        const float* gib = gi_t + (size_t)bg * G3;
        float r = sigmoidf_(gib[jg] + ghr);
        float z = sigmoidf_(gib[1024 + jg] + ghz);
        float n = tanhf(gib[2048 + jg] + r * ghn);
        float h = h_in[(size_t)bg * 1024 + jg];
        float hn = (1.0f - z) * n + z * h;
        h_out[(size_t)bg * 1024 + jg] = hn;
        if (out_f32) out_f32[(size_t)bg * 1024 + jg] = hn;
        if (out_hi) {
            bf16_t a, bb; split2(hn, a, bb);
            out_hi[(size_t)bg * 1024 + jg] = a;
            out_lo[(size_t)bg * 1024 + jg] = bb;
        }
        if (hn_out) hn_out[(size_t)bg * 1024 + jg] = hn;
    }
}

extern "C" void kernel_launch(void* const* d_in, const int* in_sizes, int n_in,
                              void* d_out, int out_size, void* d_ws, size_t ws_size,
                              hipStream_t stream)
{
    (void)in_sizes; (void)n_in; (void)out_size;
    const float* x   = (const float*)d_in[0];
    const float* h0  = (const float*)d_in[1];
    const float* Wi  = (const float*)d_in[2];
    const float* Whw = (const float*)d_in[3];
    const float* bi  = (const float*)d_in[4];
    const float* bh  = (const float*)d_in[5];
    float* out = (float*)d_out;

    char* ws = (char*)d_ws;
    size_t off = 0;
    float*  gi    = (float*)(ws + off);  off += (size_t)CROWS * G3 * 4;           // 96 MB
    bf16_t* sx_hi = (bf16_t*)(ws + off); off += (size_t)S_LEN * BATCH * 1024 * 2; // 64 MB
    bf16_t* sx_lo = (bf16_t*)(ws + off); off += (size_t)S_LEN * BATCH * 1024 * 2;
    bf16_t* wi_hi = (bf16_t*)(ws + off); off += (size_t)NLAYER * G3 * 1024 * 2;   // 12 MB
    bf16_t* wi_lo = (bf16_t*)(ws + off); off += (size_t)NLAYER * G3 * 1024 * 2;
    bf16_t* wh_hi = (bf16_t*)(ws + off); off += (size_t)NLAYER * G3 * 1024 * 2;
    bf16_t* wh_lo = (bf16_t*)(ws + off); off += (size_t)NLAYER * G3 * 1024 * 2;
    float*  hb0   = (float*)(ws + off);  off += (size_t)BATCH * 1024 * 4;
    float*  hb1   = (float*)(ws + off);  off += (size_t)BATCH * 1024 * 4;
    if (off > ws_size) return;  // workspace too small: fail cleanly

    // one-time splits
    split_kernel<<<2048, 256, 0, stream>>>(x, sx_hi, sx_lo, (int)((size_t)S_LEN * BATCH * 1024 / 4));
    split_kernel<<<2048, 256, 0, stream>>>(Wi, wi_hi, wi_lo, (int)((size_t)NLAYER * G3 * 1024 / 4));
    split_kernel<<<2048, 256, 0, stream>>>(Whw, wh_hi, wh_lo, (int)((size_t)NLAYER * G3 * 1024 / 4));

    for (int l = 0; l < NLAYER; ++l) {
        const bf16_t* WiH = wi_hi + (size_t)l * G3 * 1024;
        const bf16_t* WiL = wi_lo + (size_t)l * G3 * 1024;
        const bf16_t* WhH = wh_hi + (size_t)l * G3 * 1024;
        const bf16_t* WhL = wh_lo + (size_t)l * G3 * 1024;
        const float* bil = bi + (size_t)l * G3;
        const float* bhl = bh + (size_t)l * G3;
        const float* h0l = h0 + (size_t)l * BATCH * 1024;

        for (int c = 0; c < S_LEN / CS; ++c) {
            proj_kernel<<<dim3(24, 64), 256, 0, stream>>>(
                sx_hi + (size_t)c * CROWS * 1024, sx_lo + (size_t)c * CROWS * 1024,
                WiH, WiL, bil, gi);
            for (int tt = 0; tt < CS; ++tt) {
                const int t = c * CS + tt;
                const float* hin = (t == 0) ? h0l : ((t & 1) ? hb0 : hb1);
                float* hout = (t & 1) ? hb1 : hb0;
                float* outf = (l == 1) ? (out + (size_t)t * BATCH * 1024) : nullptr;
                bf16_t* ohi = (l == 0) ? (sx_hi + (size_t)t * BATCH * 1024) : nullptr;
                bf16_t* olo = (l == 0) ? (sx_lo + (size_t)t * BATCH * 1024) : nullptr;
                float* hn = (t == S_LEN - 1)
                                ? (out + (size_t)S_LEN * BATCH * 1024 + (size_t)l * BATCH * 1024)
                                : nullptr;
                const float* git = gi + (size_t)tt * BATCH * G3;
                rec_step_kernel<<<dim3(128, 2), 256, 0, stream>>>(
                    git, WhH, WhL, bhl, hin, hout, outf, ohi, olo, hn);
            }
        }
    }
}